// Round 4
// baseline (469.383 us; speedup 1.0000x reference)
//
#include <hip/hip_runtime.h>
#include <hip/hip_bf16.h>

typedef __bf16 bf16_t;
typedef __attribute__((ext_vector_type(8))) __bf16 bf16x8;
typedef __attribute__((ext_vector_type(4))) __bf16 bf16x4;
typedef __attribute__((ext_vector_type(4))) float f32x4;
typedef __attribute__((ext_vector_type(16))) float f32x16;

#define GAS __attribute__((address_space(1)))
#define LAS __attribute__((address_space(3)))

__device__ __forceinline__ void async_copy16(const bf16_t* g, bf16_t* l) {
    __builtin_amdgcn_global_load_lds((const GAS void*)g, (LAS void*)l, 16, 0, 0);
}

// ---------------------------------------------------------------------------
// fp32 -> bf16 convert, 8 elems/thread, vectorized.
// ---------------------------------------------------------------------------
__global__ __launch_bounds__(256) void convert_kernel(
    const float* __restrict__ src, bf16_t* __restrict__ dst, int n)
{
    int i = (blockIdx.x * 256 + threadIdx.x) * 8;
    if (i >= n) return;
    f32x4 f0 = *(const f32x4*)(src + i);
    f32x4 f1 = *(const f32x4*)(src + i + 4);
    bf16x8 v;
#pragma unroll
    for (int j = 0; j < 4; j++) { v[j] = (bf16_t)f0[j]; v[4 + j] = (bf16_t)f1[j]; }
    *(bf16x8*)&dst[i] = v;
}

// ---------------------------------------------------------------------------
// Mask bit-pack: [4,1,2048,2048] int32 (0/1) -> bits. One wave packs 64 ints.
// ---------------------------------------------------------------------------
__global__ __launch_bounds__(256) void pack_mask_kernel(
    const int* __restrict__ mask, unsigned long long* __restrict__ out)
{
    int i = blockIdx.x * 256 + threadIdx.x;
    unsigned long long bits = __ballot(mask[i] != 0);
    if ((threadIdx.x & 63) == 0) out[i >> 6] = bits;
}

// ---------------------------------------------------------------------------
// NT GEMM (m97 structure): out = (A[M,K] . W[N,K]^T + bias) * oscale. A,W bf16.
// MODE 0: out fp32 row-major [M][N]; MODE 1: out bf16 [b,h,s,dk];
// MODE 2: out bf16 [b,h,dk,s] (V^T) via mfma operand swap.
// oscale folds the attention 1/sqrt(dk) into the Q projection (exact: 2^-3,
// no extra bf16 rounding error).
// ---------------------------------------------------------------------------
template<int MODE>
__global__ __launch_bounds__(256, 2) void gemm_nt(
    const bf16_t* __restrict__ A, const bf16_t* __restrict__ W,
    const float* __restrict__ bias, void* __restrict__ out_, float oscale)
{
    __shared__ __align__(16) bf16_t Als[128 * 32];
    __shared__ __align__(16) bf16_t Bls[128 * 32];

    const int tid  = threadIdx.x;
    const int wave = tid >> 6, lane = tid & 63;
    const int quad = lane >> 4, lq = lane & 15;
    const int wm = wave >> 1, wn = wave & 1;
    const int tm = blockIdx.x * 128, tn = blockIdx.y * 128;
    const int K = 1024;

    const bf16_t* gA0 = A + (size_t)(tm + wave * 32 + (lane >> 2)) * K + (lane & 3) * 8;
    const bf16_t* gA1 = gA0 + (size_t)16 * K;
    const bf16_t* gB0 = W + (size_t)(tn + wave * 32 + (lane >> 2)) * K + (lane & 3) * 8;
    const bf16_t* gB1 = gB0 + (size_t)16 * K;
    bf16_t* lA0 = &Als[(wave * 32) * 32];
    bf16_t* lA1 = &Als[(wave * 32 + 16) * 32];
    bf16_t* lB0 = &Bls[(wave * 32) * 32];
    bf16_t* lB1 = &Bls[(wave * 32 + 16) * 32];

    f32x4 acc[4][4] = {};

    for (int k0 = 0; k0 < K; k0 += 32) {
        __syncthreads();
        async_copy16(gA0, lA0);
        async_copy16(gA1, lA1);
        async_copy16(gB0, lB0);
        async_copy16(gB1, lB1);
        gA0 += 32; gA1 += 32; gB0 += 32; gB1 += 32;
        __syncthreads();

        bf16x8 af[4], bfr[4];
#pragma unroll
        for (int i = 0; i < 4; i++) {
            af[i]  = *(const bf16x8*)&Als[(wm * 64 + i * 16 + lq) * 32 + quad * 8];
            bfr[i] = *(const bf16x8*)&Bls[(wn * 64 + i * 16 + lq) * 32 + quad * 8];
        }
#pragma unroll
        for (int i = 0; i < 4; i++)
#pragma unroll
            for (int j = 0; j < 4; j++) {
                if (MODE == 2)
                    acc[i][j] = __builtin_amdgcn_mfma_f32_16x16x32_bf16(bfr[j], af[i], acc[i][j], 0, 0, 0);
                else
                    acc[i][j] = __builtin_amdgcn_mfma_f32_16x16x32_bf16(af[i], bfr[j], acc[i][j], 0, 0, 0);
            }
    }

    float* outf = (float*)out_;
    bf16_t* outb = (bf16_t*)out_;
#pragma unroll
    for (int i = 0; i < 4; i++)
#pragma unroll
        for (int j = 0; j < 4; j++)
#pragma unroll
            for (int r = 0; r < 4; r++) {
                float v = acc[i][j][r];
                if (MODE == 0) {
                    int row = tm + wm * 64 + i * 16 + quad * 4 + r;
                    int col = tn + wn * 64 + j * 16 + lq;
                    outf[(size_t)row * 1024 + col] = (v + bias[col]) * oscale;
                } else if (MODE == 1) {
                    int row = tm + wm * 64 + i * 16 + quad * 4 + r;  // m = b*2048+s
                    int col = tn + wn * 64 + j * 16 + lq;            // n -> (h,dk)
                    v = (v + bias[col]) * oscale;
                    int b = row >> 11, s = row & 2047;
                    int h = col >> 6,  dk = col & 63;
                    outb[(((size_t)(b * 16 + h) * 2048 + s) << 6) + dk] = (bf16_t)v;
                } else {
                    int n = tn + wn * 64 + j * 16 + quad * 4 + r;    // W row
                    int m = tm + wm * 64 + i * 16 + lq;              // X row
                    v = (v + bias[n]) * oscale;
                    int b = m >> 11, s = m & 2047;
                    int h = n >> 6,  dk = n & 63;
                    outb[((size_t)((b * 16 + h) * 64 + dk) << 11) + s] = (bf16_t)v;
                }
            }
}

// ---------------------------------------------------------------------------
// Flash attention, 32x32 S^T formulation, P via wave-private LDS (no asm).
// grid (S/256, B*H), 4 waves, wave = 64 q (2 q-groups of 32). Key tile = 64.
// Q,K: [bh][2048][64]; Vt: [bh][64][2048]; X out: [b][s][h*64+dk] bf16.
//
// S^T tile = mfma_32x32x16(K, Q): lane(hi=l>>5, c=l&31) holds
//   S^T[key = (reg&3)+8*(reg>>2)+4*hi + 32*kh][q = qbase + (l&31)]
// => every score in a lane shares ONE q: softmax sum is a per-lane scalar,
//    reduced with one shfl_xor(32) at the end.
// z[4p..4p+3] are 4 CONSECUTIVE keys (8p+4hi..+3): P^T stored transposed as
// Pq[q][key] with one ds_write_b64 per p; the PV B-operand read
// Pq[q][kh*32 + c*16 + 8*hi + j] is then a contiguous ds_read_b128.
// O^T[d][q] accumulated via mfma_32x32x16(V^T, P^T); q = lane&31 per lane
// => 1/l normalize is scalar per lane. Each K/V/P fragment read feeds both
// q-groups (halves LDS traffic per FLOP vs 32q waves).
//
// K/V tiles in LDS shared by all 4 waves; reg-staged with async-split
// (next tile's global loads issued right after the barrier, hidden under
// compute). XOR swizzle (16B slot ^= row&8, write and read sides) breaks
// the stride-144B 4-way frag-read conflict.
// Q prescaled by exact 0.125 in its projection; p = __expf(s).
// ---------------------------------------------------------------------------
#define LDK 72   // Kls [key][d], 144 B rows
#define LDV 72   // Vls [d][key], 144 B rows
#define LDP 68   // Pq  [q][key] per wave, 136 B rows (2-way bank alias = free)

__global__ __launch_bounds__(256, 2) void attn_kernel(
    const bf16_t* __restrict__ Q, const bf16_t* __restrict__ Kh,
    const bf16_t* __restrict__ Vt, const unsigned int* __restrict__ mp,
    bf16_t* __restrict__ X)
{
    __shared__ __align__(16) bf16_t Kls[64 * LDK];
    __shared__ __align__(16) bf16_t Vls[64 * LDV];
    __shared__ __align__(16) bf16_t Pls[4][64 * LDP];

    const int tid  = threadIdx.x;
    const int wave = tid >> 6, lane = tid & 63;
    const int l31  = lane & 31;
    const int hi8  = (lane >> 5) * 8, hi4 = (lane >> 5) * 4;
    const int xr8  = lane & 8;            // row&8 for rows = *32 + l31
    const int bh = blockIdx.y;
    const int b  = bh >> 4, h = bh & 15;
    const int qb = blockIdx.x * 256 + wave * 64;

    // Q fragments: 2 q-groups x 4 d-chunks; lane holds Q[q=qb+qg*32+l31][c*16+hi8..+7]
    bf16x8 qf[2][4];
#pragma unroll
    for (int qg = 0; qg < 2; qg++) {
        const bf16_t* qp = Q + ((size_t)bh * 2048 + qb + qg * 32 + l31) * 64 + hi8;
#pragma unroll
        for (int c = 0; c < 4; c++) qf[qg][c] = *(const bf16x8*)(qp + c * 16);
    }

    f32x16 od[2][2] = {};     // O^T accumulators: [qg][dt(d 0..31 / 32..63)]
    float lsum[2] = {0.f, 0.f};

    // staging: 32 rows x 8 chunks, 2 row-halves per thread (K and V tiles 64x64)
    const int sr = tid >> 3, sc = tid & 7;
    const bf16_t* gK0 = Kh + ((size_t)bh * 2048 + sr) * 64 + sc * 8;
    const bf16_t* gK1 = gK0 + 32 * 64;
    const bf16_t* gV0 = Vt + ((size_t)bh * 64 + sr) * 2048 + sc * 8;
    const bf16_t* gV1 = gV0 + 32 * 2048;
    const int swc = (sc * 8) ^ (sr & 8);  // write-side swizzle ((sr+32)&8 == sr&8)
    bf16_t* lK0 = &Kls[sr * LDK + swc];
    bf16_t* lK1 = &Kls[(sr + 32) * LDK + swc];
    bf16_t* lV0 = &Vls[sr * LDV + swc];
    bf16_t* lV1 = &Vls[(sr + 32) * LDV + swc];

    // packed mask as u64/row-tile: row (b, q) has 32 u64 words of 64 key-bits
    const unsigned long long* mq0 =
        (const unsigned long long*)mp + ((size_t)(b << 11) + qb + l31) * 32;
    const unsigned long long* mq1 = mq0 + 32 * 32;   // q + 32 rows

    // prologue: stage tile 0 into registers
    bf16x8 ks0 = *(const bf16x8*)gK0, ks1 = *(const bf16x8*)gK1;
    bf16x8 vs0 = *(const bf16x8*)gV0, vs1 = *(const bf16x8*)gV1;

    bf16_t* pw = &Pls[wave][0];

    for (int kt = 0; kt < 32; kt++) {
        __syncthreads();
        *(bf16x8*)lK0 = ks0; *(bf16x8*)lK1 = ks1;
        *(bf16x8*)lV0 = vs0; *(bf16x8*)lV1 = vs1;
        __syncthreads();
        if (kt < 31) {        // async-split: next tile's loads hide under compute
            gK0 += 4096; gK1 += 4096; gV0 += 64; gV1 += 64;
            ks0 = *(const bf16x8*)gK0; ks1 = *(const bf16x8*)gK1;
            vs0 = *(const bf16x8*)gV0; vs1 = *(const bf16x8*)gV1;
        }
        unsigned long long mw[2] = { mq0[kt], mq1[kt] };

#pragma unroll
        for (int kh = 0; kh < 2; kh++) {
            // K frags: lane holds K[kh*32+l31][c*16+hi8..+7] (read once, both qg)
            bf16x8 kf[4];
            const bf16_t* krow = &Kls[(kh * 32 + l31) * LDK];
#pragma unroll
            for (int c = 0; c < 4; c++)
                kf[c] = *(const bf16x8*)(krow + ((c * 16 + hi8) ^ xr8));

#pragma unroll
            for (int qg = 0; qg < 2; qg++) {
                f32x16 z = {};
                z = __builtin_amdgcn_mfma_f32_32x32x16_bf16(kf[0], qf[qg][0], z, 0, 0, 0);
                z = __builtin_amdgcn_mfma_f32_32x32x16_bf16(kf[1], qf[qg][1], z, 0, 0, 0);
                z = __builtin_amdgcn_mfma_f32_32x32x16_bf16(kf[2], qf[qg][2], z, 0, 0, 0);
                z = __builtin_amdgcn_mfma_f32_32x32x16_bf16(kf[3], qf[qg][3], z, 0, 0, 0);
                // lane: q fixed; local key = (reg&3) + 8*(reg>>2) + 4*hi
                unsigned int mbits = (unsigned int)(mw[qg] >> (kh * 32 + hi4));
                float ls = 0.f;
#pragma unroll
                for (int p = 0; p < 4; p++) {
                    bf16x4 pk;
#pragma unroll
                    for (int r = 0; r < 4; r++) {
                        float sv = ((mbits >> (8 * p + r)) & 1) ? z[4 * p + r] : -1e9f;
                        float e = __expf(sv);
                        ls += e;
                        pk[r] = (bf16_t)e;
                    }
                    // 4 consecutive keys: one b64 store at Pq[q][kh*32+8p+4hi]
                    *(bf16x4*)&pw[(qg * 32 + l31) * LDP + kh * 32 + 8 * p + hi4] = pk;
                }
                lsum[qg] += ls;
            }

            // O^T += V^T . P^T ; V frags shared by both q-groups
            bf16x8 pf[2][2];
#pragma unroll
            for (int qg = 0; qg < 2; qg++) {
                const bf16_t* prow = &pw[(qg * 32 + l31) * LDP + kh * 32 + hi8];
                pf[qg][0] = *(const bf16x8*)(prow);
                pf[qg][1] = *(const bf16x8*)(prow + 16);
            }
#pragma unroll
            for (int c = 0; c < 2; c++)
#pragma unroll
                for (int dt = 0; dt < 2; dt++) {
                    bf16x8 vf = *(const bf16x8*)&Vls[(dt * 32 + l31) * LDV +
                                                     ((kh * 32 + c * 16 + hi8) ^ xr8)];
                    od[0][dt] = __builtin_amdgcn_mfma_f32_32x32x16_bf16(vf, pf[0][c], od[0][dt], 0, 0, 0);
                    od[1][dt] = __builtin_amdgcn_mfma_f32_32x32x16_bf16(vf, pf[1][c], od[1][dt], 0, 0, 0);
                }
        }
    }

    // normalize + write: q = qb + qg*32 + l31 per lane; d = dt*32 + 8p + hi4 + r
#pragma unroll
    for (int qg = 0; qg < 2; qg++) {
        float l = lsum[qg] + __shfl_xor(lsum[qg], 32);
        float rl = (l > 0.f) ? 1.0f / l : 0.f;
        int qrow = qb + qg * 32 + l31;
        bf16_t* xp = X + ((size_t)(b * 2048) + qrow) * 1024 + h * 64 + hi4;
#pragma unroll
        for (int dt = 0; dt < 2; dt++)
#pragma unroll
            for (int p = 0; p < 4; p++) {
                bf16x4 ov;
#pragma unroll
                for (int r = 0; r < 4; r++)
                    ov[r] = (bf16_t)(od[qg][dt][p * 4 + r] * rl);
                *(bf16x4*)(xp + dt * 32 + p * 8) = ov;
            }
    }
}

// ---------------------------------------------------------------------------
extern "C" void kernel_launch(void* const* d_in, const int* in_sizes, int n_in,
                              void* d_out, int out_size, void* d_ws, size_t ws_size,
                              hipStream_t stream)
{
    const float* query  = (const float*)d_in[0];
    const float* key_in = (const float*)d_in[1];
    const float* value  = (const float*)d_in[2];
    const int*   mask   = (const int*)d_in[3];

    char* ws = (char*)d_ws;
    const size_t SZ  = (size_t)8192 * 1024 * 2;  // one [8192,1024] bf16 buffer
    const size_t MPK = (size_t)2 * 1024 * 1024;  // packed mask bits
    const size_t WSZ = (size_t)1024 * 1024 * 2;  // one bf16 weight matrix
    bf16_t* C   = (bf16_t*)(ws);                 // conv buffer, later X
    bf16_t* Qb  = (bf16_t*)(ws + SZ);
    bf16_t* Kb  = (bf16_t*)(ws + 2 * SZ);
    bf16_t* Vtb = (bf16_t*)(ws + 3 * SZ);
    unsigned long long* mpack = (unsigned long long*)(ws + 4 * SZ);
    bf16_t* Wc[4];
    for (int i = 0; i < 4; i++)
        Wc[i] = (bf16_t*)(ws + 4 * SZ + MPK + i * WSZ);

    const size_t NEED = 4 * SZ + MPK + 4 * WSZ;
    if (ws_size < NEED) return;

    const int NACT = 8192 * 1024;
    for (int i = 0; i < 4; i++)
        convert_kernel<<<512, 256, 0, stream>>>((const float*)d_in[4 + 2 * i],
                                                Wc[i], 1024 * 1024);
    pack_mask_kernel<<<65536, 256, 0, stream>>>(mask, mpack);

    dim3 gg(64, 8);
    // C is reused serially: q -> GEMM, k -> GEMM, v -> GEMM, then X.
    // Q projection folds exact 1/sqrt(dk) = 0.125 (power of two, no extra
    // bf16 rounding); attn uses __expf.
    convert_kernel<<<4096, 256, 0, stream>>>(query, C, NACT);
    gemm_nt<1><<<gg, 256, 0, stream>>>(C, Wc[0], (const float*)d_in[5], Qb, 0.125f);
    convert_kernel<<<4096, 256, 0, stream>>>(key_in, C, NACT);
    gemm_nt<1><<<gg, 256, 0, stream>>>(C, Wc[1], (const float*)d_in[7], Kb, 1.0f);
    convert_kernel<<<4096, 256, 0, stream>>>(value, C, NACT);
    gemm_nt<2><<<gg, 256, 0, stream>>>(C, Wc[2], (const float*)d_in[9], Vtb, 1.0f);

    attn_kernel<<<dim3(8, 64), 256, 0, stream>>>(Qb, Kb, Vtb,
                                                 (const unsigned int*)mpack, C);
    gemm_nt<0><<<gg, 256, 0, stream>>>(C, Wc[3], (const float*)d_in[11], d_out, 1.0f);
}